// Round 11
// baseline (240.741 us; speedup 1.0000x reference)
//
#include <hip/hip_runtime.h>
#include <hip/hip_bf16.h>

using bf16 = __hip_bfloat16;

typedef __attribute__((ext_vector_type(8))) __bf16 bf16x8;
typedef __attribute__((ext_vector_type(4))) float floatx4;

#define EPS 1e-6f

#define RAW_BARRIER()  asm volatile("s_barrier" ::: "memory")
#define WAIT_VM8()     asm volatile("s_waitcnt vmcnt(8)" ::: "memory")
#define WAIT_VM4()     asm volatile("s_waitcnt vmcnt(4)" ::: "memory")
#define WAIT_VM0()     asm volatile("s_waitcnt vmcnt(0)" ::: "memory")
#define SCHED_FENCE()  __builtin_amdgcn_sched_barrier(0)
#define PRIO1()        __builtin_amdgcn_s_setprio(1)
#define PRIO0()        __builtin_amdgcn_s_setprio(0)

__device__ __forceinline__ void load_lds16(const void* g, void* l) {
    __builtin_amdgcn_global_load_lds(
        (const __attribute__((address_space(1))) void*)g,
        (__attribute__((address_space(3))) void*)l, 16, 0, 0);
}

__device__ __forceinline__ void storeOut(float* p, float v) { *p = v; }
__device__ __forceinline__ void storeOut(bf16* p, float v) { *p = __float2bfloat16(v); }

#define MFMA16(a, b, c) __builtin_amdgcn_mfma_f32_16x16x32_bf16(a, b, c, 0, 0, 0)

// ---------------------------------------------------------------------------
// 2-blocks/CU pipelined NT GEMM: D[m][n] = sum_k A[m][k] * B[n][k]
// BM=BN=128, BK=64 (k-half split), 256 threads = 4 waves (2M x 2N).
// (Unchanged — used for QKV projection and output projection.)
// ---------------------------------------------------------------------------
template <int BIAS_MODE, int RESID_EN, int QKV, typename OutT>
__global__ __launch_bounds__(256, 2) void gemm2b(
    const bf16* __restrict__ A, long long aStride, int lda,
    const bf16* __restrict__ B, long long bStride, int ldb,
    OutT* __restrict__ D, long long dStride, int ldd,
    bf16* __restrict__ vout, long long vStride,
    const float* __restrict__ bias,
    const float* __restrict__ resid, long long rStride, int ldr,
    int K, int tpb, int gx)
{
    constexpr int HB = 8192;   // bytes per (buf, khalf) per operand: 128x32x2B
    extern __shared__ char smem[];

    const unsigned chunk = gridDim.x >> 3;
    const unsigned glob  = (blockIdx.x & 7) * chunk + (blockIdx.x >> 3);
    const unsigned z  = glob / (unsigned)tpb;
    const unsigned t  = glob % (unsigned)tpb;
    const int m0 = (int)(t / (unsigned)gx) << 7;
    const int n0 = (int)(t % (unsigned)gx) << 7;

    const int tid  = threadIdx.x;
    const int lane = tid & 63;
    const int wave = tid >> 6;
    const int wm   = wave >> 1;          // 0..1
    const int wn   = wave & 1;           // 0..1

    const bf16* Ab = A + (size_t)z * aStride + (size_t)m0 * lda;
    const bf16* Bb = B + (size_t)z * bStride + (size_t)n0 * ldb;

    floatx4 acc[4][4];
#pragma unroll
    for (int i = 0; i < 4; ++i)
#pragma unroll
        for (int j = 0; j < 4; ++j) acc[i][j] = (floatx4){0.f, 0.f, 0.f, 0.f};

    const int laneRow = lane & 15;
    const int laneKq  = lane >> 4;
    const int kqs16   = (laneKq ^ ((laneRow >> 1) & 3)) << 4;
    const int arow0   = wm * 64 + laneRow;
    const int brow0   = wn * 64 + laneRow;

    auto stage = [&](int kt, int h) {
        char* Adst = smem + ((kt & 1) * 2 + h) * HB;
        char* Bdst = smem + 4 * HB + ((kt & 1) * 2 + h) * HB;
        const int kb = (kt << 6) + (h << 5);
#pragma unroll
        for (int u = 0; u < 2; ++u) {
            const int idx = tid + u * 256;
            const int r  = idx >> 2;
            const int qs = (idx & 3) ^ ((idx >> 3) & 3);
            load_lds16(Ab + (size_t)r * lda + kb + qs * 8, Adst + idx * 16);
        }
#pragma unroll
        for (int u = 0; u < 2; ++u) {
            const int idx = tid + u * 256;
            const int r  = idx >> 2;
            const int qs = (idx & 3) ^ ((idx >> 3) & 3);
            load_lds16(Bb + (size_t)r * ldb + kb + qs * 8, Bdst + idx * 16);
        }
    };

    const int nt = K >> 6;
    stage(0, 0); stage(0, 1); stage(1, 0);

    for (int kt = 0; kt < nt; ++kt) {
        const char* Ablk = smem + (kt & 1) * 2 * HB;
        const char* Bblk = smem + 4 * HB + (kt & 1) * 2 * HB;
        const bool lastT = (kt == nt - 1);

        // ---- phase 1: k-half 0 ----
        if (lastT) WAIT_VM4(); else WAIT_VM8();
        RAW_BARRIER();
        bf16x8 af[4], bfr[4];
#pragma unroll
        for (int im = 0; im < 4; ++im)
            af[im] = *(const bf16x8*)(Ablk + (arow0 + im * 16) * 64 + kqs16);
#pragma unroll
        for (int in = 0; in < 4; ++in)
            bfr[in] = *(const bf16x8*)(Bblk + (brow0 + in * 16) * 64 + kqs16);
        if (kt + 1 < nt) stage(kt + 1, 1);
        RAW_BARRIER();
        PRIO1();
#pragma unroll
        for (int im = 0; im < 4; ++im)
#pragma unroll
            for (int in = 0; in < 4; ++in)
                acc[im][in] = MFMA16(af[im], bfr[in], acc[im][in]);
        PRIO0();

        // ---- phase 2: k-half 1 ----
        if (lastT) WAIT_VM0(); else WAIT_VM8();
        RAW_BARRIER();
#pragma unroll
        for (int im = 0; im < 4; ++im)
            af[im] = *(const bf16x8*)(Ablk + HB + (arow0 + im * 16) * 64 + kqs16);
#pragma unroll
        for (int in = 0; in < 4; ++in)
            bfr[in] = *(const bf16x8*)(Bblk + HB + (brow0 + in * 16) * 64 + kqs16);
        if (kt + 2 < nt) stage(kt + 2, 0);
        RAW_BARRIER();
        PRIO1();
#pragma unroll
        for (int im = 0; im < 4; ++im)
#pragma unroll
            for (int in = 0; in < 4; ++in)
                acc[im][in] = MFMA16(af[im], bfr[in], acc[im][in]);
        PRIO0();
    }

    // Epilogue. C/D frag layout: col = lane&15, row = (lane>>4)*4 + reg
    const size_t dbase = (size_t)z * dStride;
#pragma unroll
    for (int im = 0; im < 4; ++im) {
        const int gmb = m0 + wm * 64 + im * 16 + (laneKq << 2);
#pragma unroll
        for (int in = 0; in < 4; ++in) {
            const int gn = n0 + wn * 64 + in * 16 + laneRow;
            float bn = 0.f;
            if (BIAS_MODE == 2) bn = bias[gn];
            if (QKV && n0 >= 1024) {
                union { bf16 h[4]; ushort4 u; } pk;
#pragma unroll
                for (int r = 0; r < 4; ++r)
                    pk.h[r] = __float2bfloat16(acc[im][in][r] + bn);
                *(ushort4*)(vout + (size_t)z * vStride +
                            (size_t)(gn - 1024) * 1024 + gmb) = pk.u;
            } else {
#pragma unroll
                for (int r = 0; r < 4; ++r) {
                    const int gm = gmb + r;
                    float v = acc[im][in][r];
                    if (BIAS_MODE == 1) v += bias[gm];
                    if (BIAS_MODE == 2) v += bn;
                    if (RESID_EN)
                        v += resid[(size_t)z * rStride + (size_t)gm * ldr + gn];
                    storeOut(D + dbase + (size_t)gm * ldd + gn, v);
                }
            }
        }
    }
}

// ---------------------------------------------------------------------------
// Fused attention v7 = v6 (R10, 62.5us, passing) + V-direct-from-L2 +
// K triple-buffer (2 barriers/tile).
//   S'[j][i] = K_j . Q_i (swapped), P = exp(scale*S'), rowsum[i] += P,
//   O[c][i] += V[c][j] * P[j][i], O2[i][c] = O / rowsum.
// v6 remaining gap: 4730 cy/tile vs ~2800 LDS model. v7 cuts LDS work:
//  - V skips LDS entirely. With the c-split, wave w's PV fragment
//    V[c=64w+16mf+laneRow][j=laneKq*8..+8] is a PRIVATE (read-once per CU,
//    no duplication — unlike R5/R6's mistake) coalesced load: 16 rows x
//    64B = 16 full lines. 4 transient vf regs; loaded for tile t+1 at the
//    bottom of tile t (after PV freed the regs), lands under tile t+1's QK.
//    Removes 32 ds_reads + 32KB LDS-write staging per tile per CU.
//  - K TRIPLE-buffered (3x32KB): stageK(t+2) at bottom of t writes the slot
//    last read at t-1; every wave passed t's top barrier => done with t-1.
//    No WAR barrier needed: 2 barriers/tile (top, post-P-write).
//  - vmcnt ledger (issue order: K0,K1,V0 | bottom of t: V(t+1),K(t+2)):
//    top of t: outstanding {V(t),K(t+1)}=8 -> vmcnt(8) retires K(t)
//      [t=31: only {V31} may remain -> vmcnt(4), else K31 could race];
//    pre-PV: vmcnt(4) retires V(t) (older than K(t+1)), keeps K(t+1)
//      [t=31: vmcnt(0)]. V needs no barrier (loader == consumer wave).
// QK split, P roundtrip (strip ih, granule (4jh+laneKq)^sw2), c-split PV,
// rowsum exchange: all byte-identical to v6 (passing).
// VGPR: qf 64 + vf 16 + pf 16 + temps (~120 arch) + acc 64 AGPR.
// ---------------------------------------------------------------------------
__global__ __launch_bounds__(512, 2) void fattn(
    const bf16* __restrict__ qkT,   // (B,1024,1024): row i = [q_i | k_i]
    const bf16* __restrict__ vv,    // (B,512,1024): [c][j]
    bf16* __restrict__ O2,          // (B,1024,512): [i][c]
    float scale)
{
    constexpr int KT = 32768;           // one K-tile: 32j x 512k bf16 = 32KB
    extern __shared__ char smem[];      // 3 x KT (K triple buffer) = 96KB
    __shared__ __align__(16) char plds[4 * 1024];   // P: 4 strips [16 i][32 j]
    __shared__ float rsLDS[2][64];

    const int bid  = blockIdx.x;
    const int glob = (bid & 7) * 32 + (bid >> 3);   // XCD-chunked (256 blocks)
    const int b    = glob >> 4;
    const int i0   = (glob & 15) << 6;

    const int tid     = threadIdx.x;
    const int lane    = tid & 63;
    const int wave    = tid >> 6;       // 0..7
    const int jh      = wave & 1;       // j-half owner in QK
    const int ih      = wave >> 1;      // i-quarter owner in QK (0..3)
    const int laneRow = lane & 15;
    const int laneKq  = lane >> 4;
    const int kqs16   = (laneKq ^ ((laneRow >> 1) & 3)) << 4;
    const int sw2     = ((laneRow >> 1) & 3) << 1;  // 8B-granule XOR mask

    const bf16* Qb = qkT + (size_t)b * 1048576 +
                     (size_t)(i0 + ih * 16 + laneRow) * 1024;
    const bf16* Kb = qkT + (size_t)b * 1048576 + 512;
    // V base for this wave's c-slice: c = wave*64 + laneRow (+16*mf later)
    const bf16* Vb = vv + (size_t)b * 524288 +
                     (size_t)(wave * 64 + laneRow) * 1024 + laneKq * 8;

    // Q fragments: i = i0 + 16*ih + laneRow, k = ks*32 + laneKq*8..+8
    bf16x8 qf[16];
#pragma unroll
    for (int ks = 0; ks < 16; ++ks)
        qf[ks] = *(const bf16x8*)(Qb + ks * 32 + laneKq * 8);

    // acc[mf][ni]: c = wave*64 + mf*16 + 4*laneKq + r, i = 16*ni + laneRow
    floatx4 acc[4][4];
#pragma unroll
    for (int mf = 0; mf < 4; ++mf)
#pragma unroll
        for (int ni = 0; ni < 4; ++ni) acc[mf][ni] = (floatx4){0.f, 0.f, 0.f, 0.f};
    float rs = 0.f;

    auto stageK = [&](int jt) {
        char* dst = smem + (jt % 3) * KT;
        const bf16* src = Kb + ((size_t)jt << 5) * 1024;
#pragma unroll
        for (int u = 0; u < 4; ++u) {
            const int idx = tid + u * 512;          // 0..2047
            const int kk = idx >> 7;                // k sub-block 0..15
            const int j  = (idx >> 2) & 31;
            const int p  = idx & 3;
            load_lds16(src + (size_t)j * 1024 + kk * 32 + 8 * (p ^ ((j >> 1) & 3)),
                       dst + idx * 16);
        }
    };

    bf16x8 vf[4];
    auto loadV = [&](int jt) {
        const bf16* vs = Vb + (jt << 5);
#pragma unroll
        for (int mf = 0; mf < 4; ++mf)
            vf[mf] = *(const bf16x8*)(vs + (size_t)mf * 16384);
    };

    // Prologue (issue order = ledger): K(0) x4, K(1) x4, V(0) x4.
    stageK(0);
    stageK(1);
    SCHED_FENCE();
    loadV(0);
    SCHED_FENCE();

    for (int jt = 0; jt < 32; ++jt) {
        // top: retire K(jt). Outstanding afterwards: {V(jt), K(jt+1)}.
        if (jt == 31) WAIT_VM4(); else WAIT_VM8();
        RAW_BARRIER();
        const char* Kt = smem + (jt % 3) * KT;

        // ---- S'[16 j (jh)][16 i (ih)] ----
        floatx4 s = (floatx4){0.f, 0.f, 0.f, 0.f};
#pragma unroll
        for (int ks = 0; ks < 16; ++ks) {
            bf16x8 kf = *(const bf16x8*)(Kt + ks * 2048 +
                                         (jh * 16 + laneRow) * 64 + kqs16);
            s = MFMA16(kf, qf[ks], s);
        }

        // ---- exp + rowsum + P write (strip ih, granule (4jh+laneKq)^sw2) ----
        union { bf16 h[4]; unsigned long long u; } w;
#pragma unroll
        for (int r = 0; r < 4; ++r) {
            float v = __expf(s[r] * scale);
            rs += v;
            w.h[r] = __float2bfloat16(v);
        }
        *(unsigned long long*)(plds + ih * 1024 + laneRow * 64 +
                               ((4 * jh + laneKq) ^ sw2) * 8) = w.u;
        asm volatile("s_waitcnt lgkmcnt(0)" ::: "memory");
        RAW_BARRIER();                   // P visible to all waves
        SCHED_FENCE();
        bf16x8 pf[4];
#pragma unroll
        for (int ni = 0; ni < 4; ++ni)
            pf[ni] = *(const bf16x8*)(plds + ni * 1024 + laneRow * 64 + kqs16);

        // retire V(jt); keep K(jt+1) in flight (V older per issue order)
        if (jt == 31) WAIT_VM0(); else WAIT_VM4();

        // ---- O[c (own 64)][all 64 i] += V . P ----
        PRIO1();
#pragma unroll
        for (int mf = 0; mf < 4; ++mf)
#pragma unroll
            for (int ni = 0; ni < 4; ++ni)
                acc[mf][ni] = MFMA16(vf[mf], pf[ni], acc[mf][ni]);
        PRIO0();

        // bottom: prefetch V(jt+1) (vf regs free after PV) then K(jt+2).
        // Triple buffer: slot (jt+2)%3 was last read at tile jt-1; all
        // waves passed this tile's top barrier => done with jt-1. No WAR.
        if (jt + 1 < 32) loadV(jt + 1);
        SCHED_FENCE();
        if (jt + 2 < 32) stageK(jt + 2);
        SCHED_FENCE();
    }

    // rowsum: lane partial covers its 4 j-regs; xor-reduce over laneKq
    // groups -> per (i = laneRow, jh, ih); sum jh halves via LDS.
    rs += __shfl_xor(rs, 16);
    rs += __shfl_xor(rs, 32);
    if (lane < 16) rsLDS[jh][ih * 16 + lane] = rs;
    __syncthreads();

    // O2[i][c] = acc * ri ; c = wave*64 + mf*16 + 4laneKq + r, i = 16ni+laneRow
#pragma unroll
    for (int ni = 0; ni < 4; ++ni) {
        const int row = ni * 16 + laneRow;
        const float ri = 1.f / (rsLDS[0][row] + rsLDS[1][row]);
        bf16* Ob = O2 + (size_t)b * 524288 +
                   (size_t)(i0 + row) * 512 + wave * 64 + (laneKq << 2);
#pragma unroll
        for (int mf = 0; mf < 4; ++mf) {
            union { bf16 h[4]; ushort4 u; } pk;
#pragma unroll
            for (int r = 0; r < 4; ++r)
                pk.h[r] = __float2bfloat16(acc[mf][ni][r] * ri);
            *(ushort4*)(Ob + mf * 16) = pk.u;
        }
    }
}

// ---------------------------------------------------------------------------
// GroupNorm stats: one block per (b, g); 16 ch x 1024 = 16384 contiguous floats
// ---------------------------------------------------------------------------
__global__ __launch_bounds__(256) void gn_stats(const float* __restrict__ x,
                                                float* __restrict__ stats)
{
    const int bg = blockIdx.x;
    const float4* p = (const float4*)(x + (size_t)bg * 16384);
    float s = 0.f, ss = 0.f;
    for (int i = threadIdx.x; i < 4096; i += 256) {
        float4 v = p[i];
        s  += v.x + v.y + v.z + v.w;
        ss += v.x * v.x + v.y * v.y + v.z * v.z + v.w * v.w;
    }
#pragma unroll
    for (int off = 32; off; off >>= 1) {
        s  += __shfl_down(s, off);
        ss += __shfl_down(ss, off);
    }
    __shared__ float rsm[4], rss[4];
    const int wv = threadIdx.x >> 6;
    if ((threadIdx.x & 63) == 0) { rsm[wv] = s; rss[wv] = ss; }
    __syncthreads();
    if (threadIdx.x == 0) {
        float S  = rsm[0] + rsm[1] + rsm[2] + rsm[3];
        float SS = rss[0] + rss[1] + rss[2] + rss[3];
        float mean = S * (1.f / 16384.f);
        float var  = SS * (1.f / 16384.f) - mean * mean;
        stats[2 * bg]     = mean;
        stats[2 * bg + 1] = rsqrtf(var + EPS);
    }
}

// ---------------------------------------------------------------------------
// GN apply + transpose: x (B,512,1024) fp32 -> xnT (B,1024,512) bf16
// ---------------------------------------------------------------------------
__global__ __launch_bounds__(256) void gn_apply_t(const float* __restrict__ x,
                                                  const float* __restrict__ stats,
                                                  const float* __restrict__ gamma,
                                                  const float* __restrict__ beta,
                                                  bf16* __restrict__ xnT)
{
    __shared__ bf16 tile[32][36];
    const int b = blockIdx.z, c0 = blockIdx.y * 32, i0 = blockIdx.x * 32;
    {
        const int cc = threadIdx.x >> 3;
        const int i4 = (threadIdx.x & 7) << 2;
        const int c  = c0 + cc;
        const float mean = stats[2 * ((b << 5) + (c >> 4))];
        const float rstd = stats[2 * ((b << 5) + (c >> 4)) + 1];
        const float a  = gamma[c] * rstd;
        const float bb = beta[c] - mean * a;
        float4 v = *(const float4*)(x + (((size_t)(b * 512 + c)) << 10) + i0 + i4);
        tile[cc][i4 + 0] = __float2bfloat16(v.x * a + bb);
        tile[cc][i4 + 1] = __float2bfloat16(v.y * a + bb);
        tile[cc][i4 + 2] = __float2bfloat16(v.z * a + bb);
        tile[cc][i4 + 3] = __float2bfloat16(v.w * a + bb);
    }
    __syncthreads();
    {
        const int ii = threadIdx.x >> 3;
        const int c4 = (threadIdx.x & 7) << 2;
        union { bf16 h[4]; uint2 u; } pk;
        pk.h[0] = tile[c4 + 0][ii];
        pk.h[1] = tile[c4 + 1][ii];
        pk.h[2] = tile[c4 + 2][ii];
        pk.h[3] = tile[c4 + 3][ii];
        *((uint2*)(xnT + (((size_t)(b * 1024 + i0 + ii)) << 9) + c0 + c4)) = pk.u;
    }
}

// ---------------------------------------------------------------------------
// prep: weights fp32->bf16 (blocks 0..1023), qkv bias concat (block 1024).
// ---------------------------------------------------------------------------
__global__ __launch_bounds__(256) void prep(
    const float* __restrict__ wq, const float* __restrict__ wk,
    const float* __restrict__ wv, const float* __restrict__ wp,
    bf16* __restrict__ wqkvb, bf16* __restrict__ wpb,
    const float* __restrict__ bq, const float* __restrict__ bk,
    const float* __restrict__ bv, float* __restrict__ bqkv)
{
    const int id = blockIdx.x;
    if (id < 1024) {
        const int w = id >> 8;
        const float* src = (w == 0) ? wq : (w == 1) ? wk : (w == 2) ? wv : wp;
        bf16* dst = (w < 3) ? (wqkvb + (size_t)w * 262144) : wpb;
        const int g = (id & 255) * 256 + threadIdx.x;
        float4 v = ((const float4*)src)[g];
        union { bf16 h[4]; uint2 u; } pk;
        pk.h[0] = __float2bfloat16(v.x);
        pk.h[1] = __float2bfloat16(v.y);
        pk.h[2] = __float2bfloat16(v.z);
        pk.h[3] = __float2bfloat16(v.w);
        ((uint2*)dst)[g] = pk.u;
    } else {
        for (int t = threadIdx.x; t < 1536; t += 256)
            bqkv[t] = (t < 512) ? bq[t] : (t < 1024) ? bk[t - 512] : bv[t - 1024];
    }
}

// ---------------------------------------------------------------------------
extern "C" void kernel_launch(void* const* d_in, const int* in_sizes, int n_in,
                              void* d_out, int out_size, void* d_ws, size_t ws_size,
                              hipStream_t stream)
{
    const float* x     = (const float*)d_in[0];
    const float* gamma = (const float*)d_in[1];
    const float* beta  = (const float*)d_in[2];
    const float* wq    = (const float*)d_in[3];
    const float* bq    = (const float*)d_in[4];
    const float* wk    = (const float*)d_in[5];
    const float* bk    = (const float*)d_in[6];
    const float* wv    = (const float*)d_in[7];
    const float* bv    = (const float*)d_in[8];
    const float* wp    = (const float*)d_in[9];
    const float* bp    = (const float*)d_in[10];
    float* out = (float*)d_out;

    char* ws = (char*)d_ws;
    size_t off = 0;
    auto alloc = [&](size_t bytes) -> char* {
        char* p = ws + off;
        off += (bytes + 255) & ~(size_t)255;
        return p;
    };

    const long long S  = 1024, C = 512;
    const long long BS = S * C;
    const long long ES = S * S;

    float* stats  = (float*)alloc(512 * 2 * sizeof(float));
    float* bqkv   = (float*)alloc(1536 * sizeof(float));
    bf16* wqkvb = (bf16*)alloc((size_t)3 * C * C * 2);  // [wq; wk; wv]
    bf16* wpb   = (bf16*)alloc((size_t)C * C * 2);
    bf16* xnT   = (bf16*)alloc((size_t)16 * BS * 2);
    bf16* qkT   = (bf16*)alloc((size_t)16 * ES * 2);    // (B,1024,1024): [qT|kT]
    bf16* vv    = (bf16*)alloc((size_t)16 * BS * 2);    // (B,512,1024)
    bf16* O2    = (bf16*)alloc((size_t)16 * BS * 2);

    // Dynamic LDS caps (immediate module state; graph-capture safe).
    hipFuncSetAttribute((const void*)gemm2b<2, 0, 1, bf16>,
                        hipFuncAttributeMaxDynamicSharedMemorySize, 65536);
    hipFuncSetAttribute((const void*)gemm2b<1, 1, 0, float>,
                        hipFuncAttributeMaxDynamicSharedMemorySize, 65536);
    hipFuncSetAttribute((const void*)fattn,
                        hipFuncAttributeMaxDynamicSharedMemorySize, 98304);

    prep<<<1025, 256, 0, stream>>>(wq, wk, wv, wp, wqkvb, wpb, bq, bk, bv, bqkv);

    gn_stats<<<512, 256, 0, stream>>>(x, stats);
    gn_apply_t<<<dim3(32, 16, 16), 256, 0, stream>>>(x, stats, gamma, beta, xnT);

    // QKV proj: M=1024 (i), N=1536 ([q|k|v]), K=512, Z=16. 8x12x16 = 1536 blk.
    gemm2b<2, 0, 1, bf16><<<1536, 256, 65536, stream>>>(
        xnT, BS, 512, wqkvb, 0, 512, qkT, ES, 1024, vv, BS,
        bqkv, nullptr, 0, 0, 512, /*tpb*/96, /*gx*/12);

    const float scale = 0.044194173824159216f; // 512^-0.5
    // Fused attention: 16 batches x 16 i-tiles (64 rows) = 256 blocks,
    // 512 threads = 8 waves = 2 waves/SIMD. 96KB LDS (K triple buffer).
    fattn<<<256, 512, 98304, stream>>>(qkT, vv, O2, scale);

    // out[o][i] = sum_c wp[o][c] O2[i][c] + bp[o] + x[o][i]. 4x8 tiles x16.
    gemm2b<1, 1, 0, float><<<512, 256, 65536, stream>>>(
        wpb, 0, 512, O2, BS, 512, out, BS, 1024, nullptr, 0,
        bp, x, BS, 1024, 512, /*tpb*/32, /*gx*/8);
}

// Round 12
// 224.873 us; speedup vs baseline: 1.0706x; 1.0706x over previous
//
#include <hip/hip_runtime.h>
#include <hip/hip_bf16.h>

using bf16 = __hip_bfloat16;

typedef __attribute__((ext_vector_type(8))) __bf16 bf16x8;
typedef __attribute__((ext_vector_type(4))) float floatx4;

#define EPS 1e-6f

#define RAW_BARRIER()  asm volatile("s_barrier" ::: "memory")
#define WAIT_VM8()     asm volatile("s_waitcnt vmcnt(8)" ::: "memory")
#define WAIT_VM4()     asm volatile("s_waitcnt vmcnt(4)" ::: "memory")
#define WAIT_VM0()     asm volatile("s_waitcnt vmcnt(0)" ::: "memory")
#define PRIO1()        __builtin_amdgcn_s_setprio(1)
#define PRIO0()        __builtin_amdgcn_s_setprio(0)

__device__ __forceinline__ void load_lds16(const void* g, void* l) {
    __builtin_amdgcn_global_load_lds(
        (const __attribute__((address_space(1))) void*)g,
        (__attribute__((address_space(3))) void*)l, 16, 0, 0);
}

__device__ __forceinline__ void storeOut(float* p, float v) { *p = v; }
__device__ __forceinline__ void storeOut(bf16* p, float v) { *p = __float2bfloat16(v); }

#define MFMA16(a, b, c) __builtin_amdgcn_mfma_f32_16x16x32_bf16(a, b, c, 0, 0, 0)

// ---------------------------------------------------------------------------
// 2-blocks/CU pipelined NT GEMM: D[m][n] = sum_k A[m][k] * B[n][k]
// BM=BN=128, BK=64 (k-half split), 256 threads = 4 waves (2M x 2N).
// Wave tile 64x64: acc[4][4] floatx4. LDS 64KB dynamic -> 2 blocks/CU, so
// two INDEPENDENT barrier groups per CU: when one block's waves stall at a
// phase barrier, the other block's waves issue MFMA — on top of the
// counted-vmcnt pipeline and setprio.
// Per K-tile, 2 phases: {waitVM; BAR; ds_read 8 frags (k-half); stage 4
// global_load_lds; BAR; prio1; 16 MFMA; prio0}. Stage mapping: phase1(kt) ->
// (kt+1, k1) [other buf], phase2(kt) -> (kt+2, k0) [same buf]. Ledger:
// prologue 12 loads; steady-state waits both vmcnt(8) (12 in flight, ~1.5
// K-tiles deep); last tile vmcnt(4)/vmcnt(0).
// Staging layout per 8KB half (row r, kquad q): slot = r*4 + (q^((r>>1)&3));
// 4-lane quads share one 64B line (coalesced); read addr = row*64 +
// ((laneKq^((laneRow>>1)&3))<<4) -> 2-way bank aliasing (free, 0 conflicts
// measured). global_load_lds dest stays linear in lane.
// 1-D grid, XCD-aware decode. QKV: n0>=1024 -> store transposed into vout.
// ---------------------------------------------------------------------------
template <int BIAS_MODE, int SCALE_EN, int RESID_EN, int EXP_MODE,
          int ROWDIV, int QKV, typename OutT>
__global__ __launch_bounds__(256, 2) void gemm2b(
    const bf16* __restrict__ A, long long aStride, int lda,
    const bf16* __restrict__ B, long long bStride, int ldb,
    OutT* __restrict__ D, long long dStride, int ldd,
    bf16* __restrict__ vout, long long vStride,
    const float* __restrict__ bias,
    const float* __restrict__ resid, long long rStride, int ldr,
    float* __restrict__ rowsum, int rsStride,
    int K, float scale, int tpb, int gx)
{
    constexpr int HB = 8192;   // bytes per (buf, khalf) per operand: 128x32x2B
    extern __shared__ char smem[];

    const unsigned chunk = gridDim.x >> 3;
    const unsigned glob  = (blockIdx.x & 7) * chunk + (blockIdx.x >> 3);
    const unsigned z  = glob / (unsigned)tpb;
    const unsigned t  = glob % (unsigned)tpb;
    const int m0 = (int)(t / (unsigned)gx) << 7;
    const int n0 = (int)(t % (unsigned)gx) << 7;

    const int tid  = threadIdx.x;
    const int lane = tid & 63;
    const int wave = tid >> 6;
    const int wm   = wave >> 1;          // 0..1
    const int wn   = wave & 1;           // 0..1

    const bf16* Ab = A + (size_t)z * aStride + (size_t)m0 * lda;
    const bf16* Bb = B + (size_t)z * bStride + (size_t)n0 * ldb;

    floatx4 acc[4][4];
#pragma unroll
    for (int i = 0; i < 4; ++i)
#pragma unroll
        for (int j = 0; j < 4; ++j) acc[i][j] = (floatx4){0.f, 0.f, 0.f, 0.f};

    const int laneRow = lane & 15;
    const int laneKq  = lane >> 4;
    const int kqs16   = (laneKq ^ ((laneRow >> 1) & 3)) << 4;
    const int arow0   = wm * 64 + laneRow;
    const int brow0   = wn * 64 + laneRow;

    // stage one (buf, khalf) pair for A and B: 2+2 load_lds16 per thread
    auto stage = [&](int kt, int h) {
        char* Adst = smem + ((kt & 1) * 2 + h) * HB;
        char* Bdst = smem + 4 * HB + ((kt & 1) * 2 + h) * HB;
        const int kb = (kt << 6) + (h << 5);
#pragma unroll
        for (int u = 0; u < 2; ++u) {
            const int idx = tid + u * 256;
            const int r  = idx >> 2;
            const int qs = (idx & 3) ^ ((idx >> 3) & 3);
            load_lds16(Ab + (size_t)r * lda + kb + qs * 8, Adst + idx * 16);
        }
#pragma unroll
        for (int u = 0; u < 2; ++u) {
            const int idx = tid + u * 256;
            const int r  = idx >> 2;
            const int qs = (idx & 3) ^ ((idx >> 3) & 3);
            load_lds16(Bb + (size_t)r * ldb + kb + qs * 8, Bdst + idx * 16);
        }
    };

    const int nt = K >> 6;
    // Prologue: tile0 both halves, tile1 k0. 12 loads outstanding.
    stage(0, 0); stage(0, 1); stage(1, 0);

    for (int kt = 0; kt < nt; ++kt) {
        const char* Ablk = smem + (kt & 1) * 2 * HB;
        const char* Bblk = smem + 4 * HB + (kt & 1) * 2 * HB;
        const bool lastT = (kt == nt - 1);

        // ---- phase 1: k-half 0 ----
        if (lastT) WAIT_VM4(); else WAIT_VM8();
        RAW_BARRIER();
        bf16x8 af[4], bfr[4];
#pragma unroll
        for (int im = 0; im < 4; ++im)
            af[im] = *(const bf16x8*)(Ablk + (arow0 + im * 16) * 64 + kqs16);
#pragma unroll
        for (int in = 0; in < 4; ++in)
            bfr[in] = *(const bf16x8*)(Bblk + (brow0 + in * 16) * 64 + kqs16);
        if (kt + 1 < nt) stage(kt + 1, 1);
        RAW_BARRIER();
        PRIO1();
#pragma unroll
        for (int im = 0; im < 4; ++im)
#pragma unroll
            for (int in = 0; in < 4; ++in)
                acc[im][in] = MFMA16(af[im], bfr[in], acc[im][in]);
        PRIO0();

        // ---- phase 2: k-half 1 ----
        if (lastT) WAIT_VM0(); else WAIT_VM8();
        RAW_BARRIER();
#pragma unroll
        for (int im = 0; im < 4; ++im)
            af[im] = *(const bf16x8*)(Ablk + HB + (arow0 + im * 16) * 64 + kqs16);
#pragma unroll
        for (int in = 0; in < 4; ++in)
            bfr[in] = *(const bf16x8*)(Bblk + HB + (brow0 + in * 16) * 64 + kqs16);
        if (kt + 2 < nt) stage(kt + 2, 0);
        RAW_BARRIER();
        PRIO1();
#pragma unroll
        for (int im = 0; im < 4; ++im)
#pragma unroll
            for (int in = 0; in < 4; ++in)
                acc[im][in] = MFMA16(af[im], bfr[in], acc[im][in]);
        PRIO0();
    }

    // Epilogue. C/D frag layout: col = lane&15, row = (lane>>4)*4 + reg
    const size_t dbase = (size_t)z * dStride;
#pragma unroll
    for (int im = 0; im < 4; ++im) {
        const int gmb = m0 + wm * 64 + im * 16 + (laneKq << 2);
        float ri[4];
        if (ROWDIV) {
#pragma unroll
            for (int r = 0; r < 4; ++r)
                ri[r] = 1.f / rowsum[(size_t)z * rsStride + gmb + r];
        }
        float rsum[4] = {0.f, 0.f, 0.f, 0.f};
#pragma unroll
        for (int in = 0; in < 4; ++in) {
            const int gn = n0 + wn * 64 + in * 16 + laneRow;
            float bn = 0.f;
            if (BIAS_MODE == 2) bn = bias[gn];
            if (QKV && n0 >= 1024) {
                union { bf16 h[4]; ushort4 u; } pk;
#pragma unroll
                for (int r = 0; r < 4; ++r)
                    pk.h[r] = __float2bfloat16(acc[im][in][r] + bn);
                *(ushort4*)(vout + (size_t)z * vStride +
                            (size_t)(gn - 1024) * 1024 + gmb) = pk.u;
            } else {
#pragma unroll
                for (int r = 0; r < 4; ++r) {
                    const int gm = gmb + r;
                    float v = acc[im][in][r];
                    if (SCALE_EN) v *= scale;
                    if (EXP_MODE) { v = __expf(v); rsum[r] += v; }
                    if (ROWDIV) v *= ri[r];
                    if (BIAS_MODE == 1) v += bias[gm];
                    if (BIAS_MODE == 2) v += bn;
                    if (RESID_EN)
                        v += resid[(size_t)z * rStride + (size_t)gm * ldr + gn];
                    storeOut(D + dbase + (size_t)gm * ldd + gn, v);
                }
            }
        }
        if (EXP_MODE) {
#pragma unroll
            for (int r = 0; r < 4; ++r) {
                float s = rsum[r];
                s += __shfl_xor(s, 1);
                s += __shfl_xor(s, 2);
                s += __shfl_xor(s, 4);
                s += __shfl_xor(s, 8);
                if (laneRow == 0)
                    atomicAdd(rowsum + (size_t)z * rsStride + gmb + r, s);
            }
        }
    }
}

// ---------------------------------------------------------------------------
// GroupNorm stats: one block per (b, g); 16 ch x 1024 = 16384 contiguous floats
// ---------------------------------------------------------------------------
__global__ __launch_bounds__(256) void gn_stats(const float* __restrict__ x,
                                                float* __restrict__ stats)
{
    const int bg = blockIdx.x;
    const float4* p = (const float4*)(x + (size_t)bg * 16384);
    float s = 0.f, ss = 0.f;
    for (int i = threadIdx.x; i < 4096; i += 256) {
        float4 v = p[i];
        s  += v.x + v.y + v.z + v.w;
        ss += v.x * v.x + v.y * v.y + v.z * v.z + v.w * v.w;
    }
#pragma unroll
    for (int off = 32; off; off >>= 1) {
        s  += __shfl_down(s, off);
        ss += __shfl_down(ss, off);
    }
    __shared__ float rs[4], rss[4];
    const int wv = threadIdx.x >> 6;
    if ((threadIdx.x & 63) == 0) { rs[wv] = s; rss[wv] = ss; }
    __syncthreads();
    if (threadIdx.x == 0) {
        float S  = rs[0] + rs[1] + rs[2] + rs[3];
        float SS = rss[0] + rss[1] + rss[2] + rss[3];
        float mean = S * (1.f / 16384.f);
        float var  = SS * (1.f / 16384.f) - mean * mean;
        stats[2 * bg]     = mean;
        stats[2 * bg + 1] = rsqrtf(var + EPS);
    }
}

// ---------------------------------------------------------------------------
// GN apply + transpose: x (B,512,1024) fp32 -> xnT (B,1024,512) bf16
// ---------------------------------------------------------------------------
__global__ __launch_bounds__(256) void gn_apply_t(const float* __restrict__ x,
                                                  const float* __restrict__ stats,
                                                  const float* __restrict__ gamma,
                                                  const float* __restrict__ beta,
                                                  bf16* __restrict__ xnT)
{
    __shared__ bf16 tile[32][36];
    const int b = blockIdx.z, c0 = blockIdx.y * 32, i0 = blockIdx.x * 32;
    {
        const int cc = threadIdx.x >> 3;
        const int i4 = (threadIdx.x & 7) << 2;
        const int c  = c0 + cc;
        const float mean = stats[2 * ((b << 5) + (c >> 4))];
        const float rstd = stats[2 * ((b << 5) + (c >> 4)) + 1];
        const float a  = gamma[c] * rstd;
        const float bb = beta[c] - mean * a;
        float4 v = *(const float4*)(x + (((size_t)(b * 512 + c)) << 10) + i0 + i4);
        tile[cc][i4 + 0] = __float2bfloat16(v.x * a + bb);
        tile[cc][i4 + 1] = __float2bfloat16(v.y * a + bb);
        tile[cc][i4 + 2] = __float2bfloat16(v.z * a + bb);
        tile[cc][i4 + 3] = __float2bfloat16(v.w * a + bb);
    }
    __syncthreads();
    {
        const int ii = threadIdx.x >> 3;
        const int c4 = (threadIdx.x & 7) << 2;
        union { bf16 h[4]; uint2 u; } pk;
        pk.h[0] = tile[c4 + 0][ii];
        pk.h[1] = tile[c4 + 1][ii];
        pk.h[2] = tile[c4 + 2][ii];
        pk.h[3] = tile[c4 + 3][ii];
        *((uint2*)(xnT + (((size_t)(b * 1024 + i0 + ii)) << 9) + c0 + c4)) = pk.u;
    }
}

// ---------------------------------------------------------------------------
// prep: weights fp32->bf16 (blocks 0..1023), qkv bias concat (block 1024),
// rowsum zero (block 1025).
// ---------------------------------------------------------------------------
__global__ __launch_bounds__(256) void prep(
    const float* __restrict__ wq, const float* __restrict__ wk,
    const float* __restrict__ wv, const float* __restrict__ wp,
    bf16* __restrict__ wqkvb, bf16* __restrict__ wpb,
    const float* __restrict__ bq, const float* __restrict__ bk,
    const float* __restrict__ bv, float* __restrict__ bqkv,
    float* __restrict__ rowsum)
{
    const int id = blockIdx.x;
    if (id < 1024) {
        const int w = id >> 8;
        const float* src = (w == 0) ? wq : (w == 1) ? wk : (w == 2) ? wv : wp;
        bf16* dst = (w < 3) ? (wqkvb + (size_t)w * 262144) : wpb;
        const int g = (id & 255) * 256 + threadIdx.x;
        float4 v = ((const float4*)src)[g];
        union { bf16 h[4]; uint2 u; } pk;
        pk.h[0] = __float2bfloat16(v.x);
        pk.h[1] = __float2bfloat16(v.y);
        pk.h[2] = __float2bfloat16(v.z);
        pk.h[3] = __float2bfloat16(v.w);
        ((uint2*)dst)[g] = pk.u;
    } else if (id == 1024) {
        for (int t = threadIdx.x; t < 1536; t += 256)
            bqkv[t] = (t < 512) ? bq[t] : (t < 1024) ? bk[t - 512] : bv[t - 1024];
    } else {
        float4 zero = {0.f, 0.f, 0.f, 0.f};
#pragma unroll
        for (int j = 0; j < 16; ++j)
            ((float4*)rowsum)[threadIdx.x + j * 256] = zero;
    }
}

// ---------------------------------------------------------------------------
extern "C" void kernel_launch(void* const* d_in, const int* in_sizes, int n_in,
                              void* d_out, int out_size, void* d_ws, size_t ws_size,
                              hipStream_t stream)
{
    const float* x     = (const float*)d_in[0];
    const float* gamma = (const float*)d_in[1];
    const float* beta  = (const float*)d_in[2];
    const float* wq    = (const float*)d_in[3];
    const float* bq    = (const float*)d_in[4];
    const float* wk    = (const float*)d_in[5];
    const float* bk    = (const float*)d_in[6];
    const float* wv    = (const float*)d_in[7];
    const float* bv    = (const float*)d_in[8];
    const float* wp    = (const float*)d_in[9];
    const float* bp    = (const float*)d_in[10];
    float* out = (float*)d_out;

    char* ws = (char*)d_ws;
    size_t off = 0;
    auto alloc = [&](size_t bytes) -> char* {
        char* p = ws + off;
        off += (bytes + 255) & ~(size_t)255;
        return p;
    };

    const long long S  = 1024, C = 512;
    const long long BS = S * C;
    const long long ES = S * S;

    float* stats  = (float*)alloc(512 * 2 * sizeof(float));
    float* bqkv   = (float*)alloc(1536 * sizeof(float));
    float* rowsum = (float*)alloc((size_t)16 * S * sizeof(float));
    bf16* wqkvb = (bf16*)alloc((size_t)3 * C * C * 2);  // [wq; wk; wv]
    bf16* wpb   = (bf16*)alloc((size_t)C * C * 2);
    bf16* xnT   = (bf16*)alloc((size_t)16 * BS * 2);
    bf16* qkT   = (bf16*)alloc((size_t)16 * ES * 2);    // (B,1024,1024): [qT|kT]
    bf16* vv    = (bf16*)alloc((size_t)16 * BS * 2);    // (B,512,1024)
    bf16* O2    = (bf16*)alloc((size_t)16 * BS * 2);

    int CB = 16;
    while (CB > 1 && off + (size_t)CB * ES * 2 + 1024 > ws_size) CB >>= 1;
    bf16* P = (bf16*)alloc((size_t)CB * ES * 2);

    // 64KB dynamic LDS (2 blocks/CU). hipFuncSetAttribute is immediate
    // module state, not a stream op (graph-capture safe).
    hipFuncSetAttribute((const void*)gemm2b<2, 0, 0, 0, 0, 1, bf16>,
                        hipFuncAttributeMaxDynamicSharedMemorySize, 65536);
    hipFuncSetAttribute((const void*)gemm2b<0, 1, 0, 1, 0, 0, bf16>,
                        hipFuncAttributeMaxDynamicSharedMemorySize, 65536);
    hipFuncSetAttribute((const void*)gemm2b<0, 0, 0, 0, 1, 0, bf16>,
                        hipFuncAttributeMaxDynamicSharedMemorySize, 65536);
    hipFuncSetAttribute((const void*)gemm2b<1, 0, 1, 0, 0, 0, float>,
                        hipFuncAttributeMaxDynamicSharedMemorySize, 65536);

    prep<<<1026, 256, 0, stream>>>(wq, wk, wv, wp, wqkvb, wpb, bq, bk, bv,
                                   bqkv, rowsum);

    gn_stats<<<512, 256, 0, stream>>>(x, stats);
    gn_apply_t<<<dim3(32, 16, 16), 256, 0, stream>>>(x, stats, gamma, beta, xnT);

    // QKV proj: M=1024 (i), N=1536 ([q|k|v]), K=512, Z=16. 8x12x16 = 1536 blk.
    gemm2b<2, 0, 0, 0, 0, 1, bf16><<<1536, 256, 65536, stream>>>(
        xnT, BS, 512, wqkvb, 0, 512, qkT, ES, 1024, vv, BS,
        bqkv, nullptr, 0, 0, nullptr, 0, 512, 1.f, /*tpb*/96, /*gx*/12);

    const float scale = 0.044194173824159216f; // 512^-0.5
    for (int b0 = 0; b0 < 16; b0 += CB) {
        // P[i][j] = exp(scale * q_i.k_j); rowsum[i] += (atomics). 8x8 tiles.
        gemm2b<0, 1, 0, 1, 0, 0, bf16><<<CB * 64, 256, 65536, stream>>>(
            qkT + (size_t)b0 * ES, ES, 1024,
            qkT + (size_t)b0 * ES + 512, ES, 1024,
            P, ES, 1024, nullptr, 0,
            nullptr, nullptr, 0, 0, rowsum + (size_t)b0 * S, (int)S,
            512, scale, /*tpb*/64, /*gx*/8);
        // O2[i][c] = (sum_j P[i][j] vv[c][j]) / rowsum[i]. 8x4 tiles, K=1024.
        gemm2b<0, 0, 0, 0, 1, 0, bf16><<<CB * 32, 256, 65536, stream>>>(
            P, ES, 1024,
            vv + (size_t)b0 * BS, BS, 1024,
            O2 + (size_t)b0 * BS, BS, 512, nullptr, 0,
            nullptr, nullptr, 0, 0, rowsum + (size_t)b0 * S, (int)S,
            1024, 1.f, /*tpb*/32, /*gx*/4);
    }

    // out[o][i] = sum_c wp[o][c] O2[i][c] + bp[o] + x[o][i]. 4x8 tiles x16.
    gemm2b<1, 0, 1, 0, 0, 0, float><<<512, 256, 65536, stream>>>(
        wpb, 0, 512, O2, BS, 512, out, BS, 1024, nullptr, 0,
        bp, x, BS, 1024, nullptr, 0, 512, 1.f, /*tpb*/32, /*gx*/8);
}

// Round 13
// 223.145 us; speedup vs baseline: 1.0789x; 1.0077x over previous
//
#include <hip/hip_runtime.h>
#include <hip/hip_bf16.h>

using bf16 = __hip_bfloat16;

typedef __attribute__((ext_vector_type(8))) __bf16 bf16x8;
typedef __attribute__((ext_vector_type(4))) float floatx4;

#define EPS 1e-6f

#define RAW_BARRIER()  asm volatile("s_barrier" ::: "memory")
#define WAIT_VM4()     asm volatile("s_waitcnt vmcnt(4)" ::: "memory")
#define WAIT_VM0()     asm volatile("s_waitcnt vmcnt(0)" ::: "memory")
#define PRIO1()        __builtin_amdgcn_s_setprio(1)
#define PRIO0()        __builtin_amdgcn_s_setprio(0)

__device__ __forceinline__ void load_lds16(const void* g, void* l) {
    __builtin_amdgcn_global_load_lds(
        (const __attribute__((address_space(1))) void*)g,
        (__attribute__((address_space(3))) void*)l, 16, 0, 0);
}

__device__ __forceinline__ void storeOut(float* p, float v) { *p = v; }
__device__ __forceinline__ void storeOut(bf16* p, float v) { *p = __float2bfloat16(v); }

#define MFMA16(a, b, c) __builtin_amdgcn_mfma_f32_16x16x32_bf16(a, b, c, 0, 0, 0)

// ---------------------------------------------------------------------------
// 5-blocks/CU pipelined NT GEMM: D[m][n] = sum_k A[m][k] * B[n][k]
// BM=BN=128, BK=32, 256 threads = 4 waves (2M x 2N), wave tile 64x64.
// vs the R3/R12 BK=64 version (2 blocks/CU, 64KB LDS): LDS halves to 32KB
// (A[2][8KB] + B[2][8KB] double buffer) -> 5 blocks/CU. Per-32k-step costs
// are IDENTICAL (4 staged loads/thread, 8 ds_reads, 16 MFMA, 2 barriers);
// the only change is 2.5x more independent barrier groups per CU, each
// staging DIFFERENT tiles (no duplicated traffic — the v5 lesson). When one
// block's waves sit at a phase barrier / vmcnt drain, another block's waves
// issue MFMA (m97 mechanism, measured 1->2 blocks/CU = 51->44us QKV).
// vmcnt ledger (4 loads per stage): prologue stage(0,1) = 8 outstanding;
// top of kt: steady outstanding {s(kt), s(kt+1)} = 8 -> vmcnt(4) retires
// s(kt); stage(kt+2) issued between read and MFMA barriers (same WAR window
// as the R1/R3 lineage, repeatedly verified); last iter vmcnt(0).
// Staging layout per 8KB buffer (row r, kquad q): slot = r*4 + (q^((r>>1)&3));
// 4-lane quads share one 64B line (coalesced); read addr = row*64 +
// ((laneKq^((laneRow>>1)&3))<<4) -> 2-way bank aliasing (free, 0 conflicts
// measured). global_load_lds dest stays linear in lane.
// 1-D grid, XCD-aware decode. QKV: n0>=1024 -> store transposed into vout.
// ---------------------------------------------------------------------------
template <int BIAS_MODE, int SCALE_EN, int RESID_EN, int EXP_MODE,
          int ROWDIV, int QKV, typename OutT>
__global__ __launch_bounds__(256, 4) void gemm2b(
    const bf16* __restrict__ A, long long aStride, int lda,
    const bf16* __restrict__ B, long long bStride, int ldb,
    OutT* __restrict__ D, long long dStride, int ldd,
    bf16* __restrict__ vout, long long vStride,
    const float* __restrict__ bias,
    const float* __restrict__ resid, long long rStride, int ldr,
    float* __restrict__ rowsum, int rsStride,
    int K, float scale, int tpb, int gx)
{
    constexpr int HB = 8192;   // bytes per buffer per operand: 128x32x2B
    extern __shared__ char smem[];   // A[2][HB] | B[2][HB] = 32KB

    const unsigned chunk = gridDim.x >> 3;
    const unsigned glob  = (blockIdx.x & 7) * chunk + (blockIdx.x >> 3);
    const unsigned z  = glob / (unsigned)tpb;
    const unsigned t  = glob % (unsigned)tpb;
    const int m0 = (int)(t / (unsigned)gx) << 7;
    const int n0 = (int)(t % (unsigned)gx) << 7;

    const int tid  = threadIdx.x;
    const int lane = tid & 63;
    const int wave = tid >> 6;
    const int wm   = wave >> 1;          // 0..1
    const int wn   = wave & 1;           // 0..1

    const bf16* Ab = A + (size_t)z * aStride + (size_t)m0 * lda;
    const bf16* Bb = B + (size_t)z * bStride + (size_t)n0 * ldb;

    floatx4 acc[4][4];
#pragma unroll
    for (int i = 0; i < 4; ++i)
#pragma unroll
        for (int j = 0; j < 4; ++j) acc[i][j] = (floatx4){0.f, 0.f, 0.f, 0.f};

    const int laneRow = lane & 15;
    const int laneKq  = lane >> 4;
    const int kqs16   = (laneKq ^ ((laneRow >> 1) & 3)) << 4;
    const int arow0   = wm * 64 + laneRow;
    const int brow0   = wn * 64 + laneRow;

    // stage one BK=32 slab for A and B: 2+2 load_lds16 per thread
    auto stage = [&](int kt) {
        char* Adst = smem + (kt & 1) * HB;
        char* Bdst = smem + 2 * HB + (kt & 1) * HB;
        const int kb = kt << 5;
#pragma unroll
        for (int u = 0; u < 2; ++u) {
            const int idx = tid + u * 256;
            const int r  = idx >> 2;
            const int qs = (idx & 3) ^ ((idx >> 3) & 3);
            load_lds16(Ab + (size_t)r * lda + kb + qs * 8, Adst + idx * 16);
        }
#pragma unroll
        for (int u = 0; u < 2; ++u) {
            const int idx = tid + u * 256;
            const int r  = idx >> 2;
            const int qs = (idx & 3) ^ ((idx >> 3) & 3);
            load_lds16(Bb + (size_t)r * ldb + kb + qs * 8, Bdst + idx * 16);
        }
    };

    const int nt = K >> 5;
    stage(0); stage(1);          // 8 loads outstanding

    for (int kt = 0; kt < nt; ++kt) {
        const bool lastT = (kt == nt - 1);
        // steady: outstanding {s(kt), s(kt+1)} = 8 -> retire s(kt).
        // last iter: only {s(kt)} outstanding -> drain fully.
        if (lastT) WAIT_VM0(); else WAIT_VM4();
        RAW_BARRIER();
        const char* Ablk = smem + (kt & 1) * HB;
        const char* Bblk = smem + 2 * HB + (kt & 1) * HB;

        bf16x8 af[4], bfr[4];
#pragma unroll
        for (int im = 0; im < 4; ++im)
            af[im] = *(const bf16x8*)(Ablk + (arow0 + im * 16) * 64 + kqs16);
#pragma unroll
        for (int in = 0; in < 4; ++in)
            bfr[in] = *(const bf16x8*)(Bblk + (brow0 + in * 16) * 64 + kqs16);
        if (kt + 2 < nt) stage(kt + 2);
        RAW_BARRIER();
        PRIO1();
#pragma unroll
        for (int im = 0; im < 4; ++im)
#pragma unroll
            for (int in = 0; in < 4; ++in)
                acc[im][in] = MFMA16(af[im], bfr[in], acc[im][in]);
        PRIO0();
    }

    // Epilogue. C/D frag layout: col = lane&15, row = (lane>>4)*4 + reg
    const size_t dbase = (size_t)z * dStride;
#pragma unroll
    for (int im = 0; im < 4; ++im) {
        const int gmb = m0 + wm * 64 + im * 16 + (laneKq << 2);
        float ri[4];
        if (ROWDIV) {
#pragma unroll
            for (int r = 0; r < 4; ++r)
                ri[r] = 1.f / rowsum[(size_t)z * rsStride + gmb + r];
        }
        float rsum[4] = {0.f, 0.f, 0.f, 0.f};
#pragma unroll
        for (int in = 0; in < 4; ++in) {
            const int gn = n0 + wn * 64 + in * 16 + laneRow;
            float bn = 0.f;
            if (BIAS_MODE == 2) bn = bias[gn];
            if (QKV && n0 >= 1024) {
                union { bf16 h[4]; ushort4 u; } pk;
#pragma unroll
                for (int r = 0; r < 4; ++r)
                    pk.h[r] = __float2bfloat16(acc[im][in][r] + bn);
                *(ushort4*)(vout + (size_t)z * vStride +
                            (size_t)(gn - 1024) * 1024 + gmb) = pk.u;
            } else {
#pragma unroll
                for (int r = 0; r < 4; ++r) {
                    const int gm = gmb + r;
                    float v = acc[im][in][r];
                    if (SCALE_EN) v *= scale;
                    if (EXP_MODE) { v = __expf(v); rsum[r] += v; }
                    if (ROWDIV) v *= ri[r];
                    if (BIAS_MODE == 1) v += bias[gm];
                    if (BIAS_MODE == 2) v += bn;
                    if (RESID_EN)
                        v += resid[(size_t)z * rStride + (size_t)gm * ldr + gn];
                    storeOut(D + dbase + (size_t)gm * ldd + gn, v);
                }
            }
        }
        if (EXP_MODE) {
#pragma unroll
            for (int r = 0; r < 4; ++r) {
                float s = rsum[r];
                s += __shfl_xor(s, 1);
                s += __shfl_xor(s, 2);
                s += __shfl_xor(s, 4);
                s += __shfl_xor(s, 8);
                if (laneRow == 0)
                    atomicAdd(rowsum + (size_t)z * rsStride + gmb + r, s);
            }
        }
    }
}

// ---------------------------------------------------------------------------
// GroupNorm stats: one block per (b, g); 16 ch x 1024 = 16384 contiguous floats
// ---------------------------------------------------------------------------
__global__ __launch_bounds__(256) void gn_stats(const float* __restrict__ x,
                                                float* __restrict__ stats)
{
    const int bg = blockIdx.x;
    const float4* p = (const float4*)(x + (size_t)bg * 16384);
    float s = 0.f, ss = 0.f;
    for (int i = threadIdx.x; i < 4096; i += 256) {
        float4 v = p[i];
        s  += v.x + v.y + v.z + v.w;
        ss += v.x * v.x + v.y * v.y + v.z * v.z + v.w * v.w;
    }
#pragma unroll
    for (int off = 32; off; off >>= 1) {
        s  += __shfl_down(s, off);
        ss += __shfl_down(ss, off);
    }
    __shared__ float rs[4], rss[4];
    const int wv = threadIdx.x >> 6;
    if ((threadIdx.x & 63) == 0) { rs[wv] = s; rss[wv] = ss; }
    __syncthreads();
    if (threadIdx.x == 0) {
        float S  = rs[0] + rs[1] + rs[2] + rs[3];
        float SS = rss[0] + rss[1] + rss[2] + rss[3];
        float mean = S * (1.f / 16384.f);
        float var  = SS * (1.f / 16384.f) - mean * mean;
        stats[2 * bg]     = mean;
        stats[2 * bg + 1] = rsqrtf(var + EPS);
    }
}

// ---------------------------------------------------------------------------
// GN apply + transpose: x (B,512,1024) fp32 -> xnT (B,1024,512) bf16
// ---------------------------------------------------------------------------
__global__ __launch_bounds__(256) void gn_apply_t(const float* __restrict__ x,
                                                  const float* __restrict__ stats,
                                                  const float* __restrict__ gamma,
                                                  const float* __restrict__ beta,
                                                  bf16* __restrict__ xnT)
{
    __shared__ bf16 tile[32][36];
    const int b = blockIdx.z, c0 = blockIdx.y * 32, i0 = blockIdx.x * 32;
    {
        const int cc = threadIdx.x >> 3;
        const int i4 = (threadIdx.x & 7) << 2;
        const int c  = c0 + cc;
        const float mean = stats[2 * ((b << 5) + (c >> 4))];
        const float rstd = stats[2 * ((b << 5) + (c >> 4)) + 1];
        const float a  = gamma[c] * rstd;
        const float bb = beta[c] - mean * a;
        float4 v = *(const float4*)(x + (((size_t)(b * 512 + c)) << 10) + i0 + i4);
        tile[cc][i4 + 0] = __float2bfloat16(v.x * a + bb);
        tile[cc][i4 + 1] = __float2bfloat16(v.y * a + bb);
        tile[cc][i4 + 2] = __float2bfloat16(v.z * a + bb);
        tile[cc][i4 + 3] = __float2bfloat16(v.w * a + bb);
    }
    __syncthreads();
    {
        const int ii = threadIdx.x >> 3;
        const int c4 = (threadIdx.x & 7) << 2;
        union { bf16 h[4]; uint2 u; } pk;
        pk.h[0] = tile[c4 + 0][ii];
        pk.h[1] = tile[c4 + 1][ii];
        pk.h[2] = tile[c4 + 2][ii];
        pk.h[3] = tile[c4 + 3][ii];
        *((uint2*)(xnT + (((size_t)(b * 1024 + i0 + ii)) << 9) + c0 + c4)) = pk.u;
    }
}

// ---------------------------------------------------------------------------
// prep: weights fp32->bf16 (blocks 0..1023), qkv bias concat (block 1024),
// rowsum zero (block 1025).
// ---------------------------------------------------------------------------
__global__ __launch_bounds__(256) void prep(
    const float* __restrict__ wq, const float* __restrict__ wk,
    const float* __restrict__ wv, const float* __restrict__ wp,
    bf16* __restrict__ wqkvb, bf16* __restrict__ wpb,
    const float* __restrict__ bq, const float* __restrict__ bk,
    const float* __restrict__ bv, float* __restrict__ bqkv,
    float* __restrict__ rowsum)
{
    const int id = blockIdx.x;
    if (id < 1024) {
        const int w = id >> 8;
        const float* src = (w == 0) ? wq : (w == 1) ? wk : (w == 2) ? wv : wp;
        bf16* dst = (w < 3) ? (wqkvb + (size_t)w * 262144) : wpb;
        const int g = (id & 255) * 256 + threadIdx.x;
        float4 v = ((const float4*)src)[g];
        union { bf16 h[4]; uint2 u; } pk;
        pk.h[0] = __float2bfloat16(v.x);
        pk.h[1] = __float2bfloat16(v.y);
        pk.h[2] = __float2bfloat16(v.z);
        pk.h[3] = __float2bfloat16(v.w);
        ((uint2*)dst)[g] = pk.u;
    } else if (id == 1024) {
        for (int t = threadIdx.x; t < 1536; t += 256)
            bqkv[t] = (t < 512) ? bq[t] : (t < 1024) ? bk[t - 512] : bv[t - 1024];
    } else {
        float4 zero = {0.f, 0.f, 0.f, 0.f};
#pragma unroll
        for (int j = 0; j < 16; ++j)
            ((float4*)rowsum)[threadIdx.x + j * 256] = zero;
    }
}

// ---------------------------------------------------------------------------
extern "C" void kernel_launch(void* const* d_in, const int* in_sizes, int n_in,
                              void* d_out, int out_size, void* d_ws, size_t ws_size,
                              hipStream_t stream)
{
    const float* x     = (const float*)d_in[0];
    const float* gamma = (const float*)d_in[1];
    const float* beta  = (const float*)d_in[2];
    const float* wq    = (const float*)d_in[3];
    const float* bq    = (const float*)d_in[4];
    const float* wk    = (const float*)d_in[5];
    const float* bk    = (const float*)d_in[6];
    const float* wv    = (const float*)d_in[7];
    const float* bv    = (const float*)d_in[8];
    const float* wp    = (const float*)d_in[9];
    const float* bp    = (const float*)d_in[10];
    float* out = (float*)d_out;

    char* ws = (char*)d_ws;
    size_t off = 0;
    auto alloc = [&](size_t bytes) -> char* {
        char* p = ws + off;
        off += (bytes + 255) & ~(size_t)255;
        return p;
    };

    const long long S  = 1024, C = 512;
    const long long BS = S * C;
    const long long ES = S * S;

    float* stats  = (float*)alloc(512 * 2 * sizeof(float));
    float* bqkv   = (float*)alloc(1536 * sizeof(float));
    float* rowsum = (float*)alloc((size_t)16 * S * sizeof(float));
    bf16* wqkvb = (bf16*)alloc((size_t)3 * C * C * 2);  // [wq; wk; wv]
    bf16* wpb   = (bf16*)alloc((size_t)C * C * 2);
    bf16* xnT   = (bf16*)alloc((size_t)16 * BS * 2);
    bf16* qkT   = (bf16*)alloc((size_t)16 * ES * 2);    // (B,1024,1024): [qT|kT]
    bf16* vv    = (bf16*)alloc((size_t)16 * BS * 2);    // (B,512,1024)
    bf16* O2    = (bf16*)alloc((size_t)16 * BS * 2);

    int CB = 16;
    while (CB > 1 && off + (size_t)CB * ES * 2 + 1024 > ws_size) CB >>= 1;
    bf16* P = (bf16*)alloc((size_t)CB * ES * 2);

    // 32KB dynamic LDS -> 5 blocks/CU. hipFuncSetAttribute is immediate
    // module state, not a stream op (graph-capture safe).
    hipFuncSetAttribute((const void*)gemm2b<2, 0, 0, 0, 0, 1, bf16>,
                        hipFuncAttributeMaxDynamicSharedMemorySize, 32768);
    hipFuncSetAttribute((const void*)gemm2b<0, 1, 0, 1, 0, 0, bf16>,
                        hipFuncAttributeMaxDynamicSharedMemorySize, 32768);
    hipFuncSetAttribute((const void*)gemm2b<0, 0, 0, 0, 1, 0, bf16>,
                        hipFuncAttributeMaxDynamicSharedMemorySize, 32768);
    hipFuncSetAttribute((const void*)gemm2b<1, 0, 1, 0, 0, 0, float>,
                        hipFuncAttributeMaxDynamicSharedMemorySize, 32768);

    prep<<<1026, 256, 0, stream>>>(wq, wk, wv, wp, wqkvb, wpb, bq, bk, bv,
                                   bqkv, rowsum);

    gn_stats<<<512, 256, 0, stream>>>(x, stats);
    gn_apply_t<<<dim3(32, 16, 16), 256, 0, stream>>>(x, stats, gamma, beta, xnT);

    // QKV proj: M=1024 (i), N=1536 ([q|k|v]), K=512, Z=16. 8x12x16 = 1536 blk.
    gemm2b<2, 0, 0, 0, 0, 1, bf16><<<1536, 256, 32768, stream>>>(
        xnT, BS, 512, wqkvb, 0, 512, qkT, ES, 1024, vv, BS,
        bqkv, nullptr, 0, 0, nullptr, 0, 512, 1.f, /*tpb*/96, /*gx*/12);

    const float scale = 0.044194173824159216f; // 512^-0.5
    for (int b0 = 0; b0 < 16; b0 += CB) {
        // P[i][j] = exp(scale * q_i.k_j); rowsum[i] += (atomics). 8x8 tiles.
        gemm2b<0, 1, 0, 1, 0, 0, bf16><<<CB * 64, 256, 32768, stream>>>(
            qkT + (size_t)b0 * ES, ES, 1024,
            qkT + (size_t)b0 * ES + 512, ES, 1024,
            P, ES, 1024, nullptr, 0,
            nullptr, nullptr, 0, 0, rowsum + (size_t)b0 * S, (int)S,
            512, scale, /*tpb*/64, /*gx*/8);
        // O2[i][c] = (sum_j P[i][j] vv[c][j]) / rowsum[i]. 8x4 tiles, K=1024.
        gemm2b<0, 0, 0, 0, 1, 0, bf16><<<CB * 32, 256, 32768, stream>>>(
            P, ES, 1024,
            vv + (size_t)b0 * BS, BS, 1024,
            O2 + (size_t)b0 * BS, BS, 512, nullptr, 0,
            nullptr, nullptr, 0, 0, rowsum + (size_t)b0 * S, (int)S,
            1024, 1.f, /*tpb*/32, /*gx*/4);
    }

    // out[o][i] = sum_c wp[o][c] O2[i][c] + bp[o] + x[o][i]. 4x8 tiles x16.
    gemm2b<1, 0, 1, 0, 0, 0, float><<<512, 256, 32768, stream>>>(
        wpb, 0, 512, O2, BS, 512, out, BS, 1024, nullptr, 0,
        bp, x, BS, 1024, nullptr, 0, 512, 1.f, /*tpb*/32, /*gx*/8);
}